// Round 1
// baseline (8141.051 us; speedup 1.0000x reference)
//
#include <hip/hip_runtime.h>
#include <math.h>

#define D    1024
#define H    16
#define DH   64
#define S    1024
#define M    1024
#define B    2
#define J    2048          // M + S
#define SCALE 0.125f       // 1/sqrt(64)

// ---------------------------------------------------------------------------
// Generic tiled fp32 GEMM: C[g, c] = sum_k A[g, k] * W[k, c],  K = 1024 always.
// BM = BN = 64, BK = 16, 256 threads, 4x4 microtile per thread.
// MODE 0: kv projection (A gathered from memory/input, split k/val outputs)
// MODE 1: q projection  (epilogue adds u and v -> qu_ws, qv_ws)
// MODE 2: r projection
// MODE 3: output projection (plain row-major store)
// ---------------------------------------------------------------------------
template<int MODE>
__global__ __launch_bounds__(256)
void gemm_k(const float* __restrict__ A0, const float* __restrict__ A1,
            const float* __restrict__ W, int ncols,
            float* __restrict__ out0, float* __restrict__ out1,
            const float* __restrict__ uvec, const float* __restrict__ vvec,
            int rowSplit)
{
    __shared__ float As[64][17];
    __shared__ float Ws[16][65];
    const int row0 = blockIdx.y * 64;
    const int col0 = blockIdx.x * 64;
    const int tid  = threadIdx.x;
    const int ty   = tid >> 4;       // 0..15 (row group)
    const int tx   = tid & 15;       // 0..15 (col group)
    float acc[4][4] = {};

    for (int k0 = 0; k0 < D; k0 += 16) {
        // load A tile: 64 rows x 16 k
        #pragma unroll
        for (int e = tid; e < 64 * 16; e += 256) {
            int rr = e >> 4, kk = e & 15;
            int g = row0 + rr;
            const float* ap;
            if (MODE == 0)
                ap = (g < rowSplit) ? (A0 + (size_t)g * D)
                                    : (A1 + (size_t)(g - rowSplit) * D);
            else
                ap = A0 + (size_t)g * D;
            As[rr][kk] = ap[k0 + kk];
        }
        // load W tile: 16 k x 64 cols
        #pragma unroll
        for (int e = tid; e < 16 * 64; e += 256) {
            int kk = e >> 6, cc = e & 63;
            Ws[kk][cc] = W[(size_t)(k0 + kk) * ncols + col0 + cc];
        }
        __syncthreads();
        #pragma unroll
        for (int kk = 0; kk < 16; ++kk) {
            float a[4], wv[4];
            #pragma unroll
            for (int r = 0; r < 4; ++r) a[r] = As[ty * 4 + r][kk];
            #pragma unroll
            for (int c = 0; c < 4; ++c) wv[c] = Ws[kk][tx * 4 + c];
            #pragma unroll
            for (int r = 0; r < 4; ++r)
                #pragma unroll
                for (int c = 0; c < 4; ++c)
                    acc[r][c] += a[r] * wv[c];
        }
        __syncthreads();
    }

    #pragma unroll
    for (int r = 0; r < 4; ++r) {
        int g = row0 + ty * 4 + r;
        #pragma unroll
        for (int c = 0; c < 4; ++c) {
            int cc = col0 + tx * 4 + c;
            float val = acc[r][c];
            if (MODE == 0) {
                int j = g >> 1, b = g & 1;           // row = j*B + b, B = 2
                if (cc < H * DH) {
                    int h = cc >> 6, d = cc & 63;
                    out0[(((size_t)b * H + h) * J + j) * DH + d] = val;
                } else {
                    int c2 = cc - H * DH;
                    int h = c2 >> 6, d = c2 & 63;
                    out1[(((size_t)b * H + h) * J + j) * DH + d] = val;
                }
            } else if (MODE == 1) {
                int i = g >> 1, b = g & 1;           // row = i*B + b
                int h = cc >> 6, d = cc & 63;
                size_t o = (((size_t)b * H + h) * S + i) * DH + d;
                out0[o] = val + uvec[cc];
                out1[o] = val + vvec[cc];
            } else if (MODE == 2) {
                int h = cc >> 6, d = cc & 63;        // row = j
                out0[((size_t)h * J + g) * DH + d] = val;
            } else {
                out0[(size_t)g * D + cc] = val;
            }
        }
    }
}

// ---------------------------------------------------------------------------
// Fused attention: one block per (i, b, h). 256 threads = 4 waves.
// Wave w handles j = w, w+4, ... Lane = d. Content: dot(qu[i], k[j]).
// Position term via analytic rel_shift: f = i*J + j + S; i2 = f/(J+1);
// jp = f%(J+1); term = (jp==0) ? 0 : dot(qv[i2], r[jp-1]).  (i2 in {i, i+1})
// Two-pass softmax over scores in LDS, then PV with cross-wave reduce.
// ---------------------------------------------------------------------------
__global__ __launch_bounds__(256)
void attn_k(const float* __restrict__ qu_ws, const float* __restrict__ qv_ws,
            const float* __restrict__ k_ws,  const float* __restrict__ v_ws,
            const float* __restrict__ r_ws,  float* __restrict__ o_ws)
{
    const int i   = blockIdx.x;          // 0..S-1
    const int bh  = blockIdx.y;          // b*H + h
    const int h   = bh & (H - 1);
    const int b   = bh >> 4;
    const int tid = threadIdx.x;
    const int w    = tid >> 6;
    const int lane = tid & 63;

    __shared__ float qu_s[DH], qv0_s[DH], qv1_s[DH];
    __shared__ float sc[J];
    __shared__ float red[4 * DH];
    __shared__ float wred[8];

    if (tid < DH)            qu_s[tid]        = qu_ws[((size_t)bh * S + i) * DH + tid];
    else if (tid < 2 * DH)   qv0_s[tid - DH]  = qv_ws[((size_t)bh * S + i) * DH + (tid - DH)];
    else if (tid < 3 * DH) {
        int d = tid - 2 * DH;
        qv1_s[d] = (i + 1 < S) ? qv_ws[((size_t)bh * S + i + 1) * DH + d] : 0.0f;
    }
    __syncthreads();

    const float qud  = qu_s[lane];
    const float qv0d = qv0_s[lane];
    const float qv1d = qv1_s[lane];
    const float* kb = k_ws + (size_t)bh * J * DH;
    const float* rb = r_ws + (size_t)h  * J * DH;

    // ---- scores ----
    for (int j = w; j < J; j += 4) {
        float s = qud * kb[(size_t)j * DH + lane];
        int f  = i * J + j + S;
        int i2 = f / (J + 1);
        int jp = f - i2 * (J + 1);
        if (jp > 0) {
            float rv = rb[(size_t)(jp - 1) * DH + lane];
            s += (i2 == i ? qv0d : qv1d) * rv;
        }
        #pragma unroll
        for (int off = 32; off; off >>= 1) s += __shfl_xor(s, off, 64);
        if (lane == 0) sc[j] = s * SCALE;
    }
    __syncthreads();

    // ---- softmax (two pass) ----
    float mx = -INFINITY;
    for (int j = tid; j < J; j += 256) mx = fmaxf(mx, sc[j]);
    #pragma unroll
    for (int off = 32; off; off >>= 1) mx = fmaxf(mx, __shfl_xor(mx, off, 64));
    if (lane == 0) wred[w] = mx;
    __syncthreads();
    mx = fmaxf(fmaxf(wred[0], wred[1]), fmaxf(wred[2], wred[3]));

    float ssum = 0.0f;
    for (int j = tid; j < J; j += 256) {
        float e = __expf(sc[j] - mx);
        sc[j] = e;
        ssum += e;
    }
    #pragma unroll
    for (int off = 32; off; off >>= 1) ssum += __shfl_xor(ssum, off, 64);
    if (lane == 0) wred[4 + w] = ssum;
    __syncthreads();
    const float inv = 1.0f / (wred[4] + wred[5] + wred[6] + wred[7]);

    // ---- PV ----
    const float* vb = v_ws + (size_t)bh * J * DH;
    float acc = 0.0f;
    for (int j = w; j < J; j += 4)
        acc += sc[j] * vb[(size_t)j * DH + lane];
    red[w * DH + lane] = acc;
    __syncthreads();
    if (tid < DH) {
        float o = (red[tid] + red[DH + tid] + red[2 * DH + tid] + red[3 * DH + tid]) * inv;
        o_ws[((size_t)i * B + b) * (H * DH) + (size_t)h * DH + tid] = o;
    }
}

// ---------------------------------------------------------------------------
extern "C" void kernel_launch(void* const* d_in, const int* in_sizes, int n_in,
                              void* d_out, int out_size, void* d_ws, size_t ws_size,
                              hipStream_t stream)
{
    const float* x    = (const float*)d_in[0];   // [S, B, D]
    const float* pemb = (const float*)d_in[1];   // [S+M, D]
    const float* mem  = (const float*)d_in[2];   // [M, B, D]
    const float* u    = (const float*)d_in[3];   // [H, DH]
    const float* v    = (const float*)d_in[4];   // [H, DH]
    const float* Wkv  = (const float*)d_in[5];   // [D, 2*H*DH]
    const float* Wq   = (const float*)d_in[6];   // [D, H*DH]
    const float* Wpos = (const float*)d_in[7];   // [D, H*DH]
    const float* Wout = (const float*)d_in[8];   // [H*DH, D]
    float* out = (float*)d_out;                  // [S, B, D]

    float* ws    = (float*)d_ws;
    float* k_ws  = ws;                                   // B*H*J*DH = 4M floats
    float* v_ws  = k_ws  + (size_t)B * H * J * DH;       // 4M
    float* qu_ws = v_ws  + (size_t)B * H * J * DH;       // 2M
    float* qv_ws = qu_ws + (size_t)B * H * S * DH;       // 2M
    float* r_ws  = qv_ws + (size_t)B * H * S * DH;       // 2M
    float* o_ws  = r_ws  + (size_t)H * J * DH;           // 2M  (total 64 MB)

    // kv projection: rows = J*B (row = j*B + b), cols = 2*H*DH
    gemm_k<0><<<dim3((2 * H * DH) / 64, (J * B) / 64), 256, 0, stream>>>(
        mem, x, Wkv, 2 * H * DH, k_ws, v_ws, nullptr, nullptr, M * B);
    // q projection (+u, +v): rows = S*B, cols = H*DH
    gemm_k<1><<<dim3((H * DH) / 64, (S * B) / 64), 256, 0, stream>>>(
        x, nullptr, Wq, H * DH, qu_ws, qv_ws, u, v, 0);
    // r projection: rows = J, cols = H*DH
    gemm_k<2><<<dim3((H * DH) / 64, J / 64), 256, 0, stream>>>(
        pemb, nullptr, Wpos, H * DH, r_ws, nullptr, nullptr, nullptr, 0);
    // fused rel-shift attention
    attn_k<<<dim3(S, B * H), 256, 0, stream>>>(qu_ws, qv_ws, k_ws, v_ws, r_ws, o_ws);
    // output projection: rows = S*B, cols = D
    gemm_k<3><<<dim3(D / 64, (S * B) / 64), 256, 0, stream>>>(
        o_ws, nullptr, Wout, D, out, nullptr, nullptr, nullptr, 0);
}

// Round 2
// 1187.413 us; speedup vs baseline: 6.8561x; 6.8561x over previous
//
#include <hip/hip_runtime.h>
#include <hip/hip_bf16.h>
#include <hip/hip_fp16.h>
#include <math.h>

#define D    1024
#define H    16
#define DH   64
#define S    1024
#define M    1024
#define B    2
#define J    2048          // M + S
#define SCALE 0.125f       // 1/sqrt(64)

typedef __attribute__((ext_vector_type(8))) short        bf16x8;
typedef __attribute__((ext_vector_type(8))) _Float16     h16x8;
typedef __attribute__((ext_vector_type(8))) unsigned short us8;
typedef __attribute__((ext_vector_type(4))) float        f32x4;

__device__ __forceinline__ unsigned short f2bf(float f) {
    __hip_bfloat16 t = __float2bfloat16(f);
    unsigned short r; __builtin_memcpy(&r, &t, 2); return r;
}

// ---------------------------------------------------------------------------
// Tiled fp32 GEMM (unchanged compute), epilogues produce bf16 attention inputs.
// MODE 0: kv proj -> k_bf [b][h][j][d] bf16, vt_bf [b][h][d][j] bf16 (V transposed)
// MODE 1: q proj  -> qu_bf/qv_bf [b][h][i][d] bf16 = (q + u|v) * SCALE
// MODE 2: r proj  -> r_bf [h][u][d] bf16
// MODE 3: out proj -> fp32 row-major
// ---------------------------------------------------------------------------
template<int MODE>
__global__ __launch_bounds__(256)
void gemm_k(const float* __restrict__ A0, const float* __restrict__ A1,
            const float* __restrict__ W, int ncols,
            void* __restrict__ out0v, void* __restrict__ out1v,
            const float* __restrict__ uvec, const float* __restrict__ vvec,
            int rowSplit)
{
    __shared__ float As[64][17];
    __shared__ float Ws[16][65];
    const int row0 = blockIdx.y * 64;
    const int col0 = blockIdx.x * 64;
    const int tid  = threadIdx.x;
    const int ty   = tid >> 4;
    const int tx   = tid & 15;
    float acc[4][4] = {};

    for (int k0 = 0; k0 < D; k0 += 16) {
        #pragma unroll
        for (int e = tid; e < 64 * 16; e += 256) {
            int rr = e >> 4, kk = e & 15;
            int g = row0 + rr;
            const float* ap;
            if (MODE == 0)
                ap = (g < rowSplit) ? (A0 + (size_t)g * D)
                                    : (A1 + (size_t)(g - rowSplit) * D);
            else
                ap = A0 + (size_t)g * D;
            As[rr][kk] = ap[k0 + kk];
        }
        #pragma unroll
        for (int e = tid; e < 16 * 64; e += 256) {
            int kk = e >> 6, cc = e & 63;
            Ws[kk][cc] = W[(size_t)(k0 + kk) * ncols + col0 + cc];
        }
        __syncthreads();
        #pragma unroll
        for (int kk = 0; kk < 16; ++kk) {
            float a[4], wv[4];
            #pragma unroll
            for (int r = 0; r < 4; ++r) a[r] = As[ty * 4 + r][kk];
            #pragma unroll
            for (int c = 0; c < 4; ++c) wv[c] = Ws[kk][tx * 4 + c];
            #pragma unroll
            for (int r = 0; r < 4; ++r)
                #pragma unroll
                for (int c = 0; c < 4; ++c)
                    acc[r][c] += a[r] * wv[c];
        }
        __syncthreads();
    }

    #pragma unroll
    for (int r = 0; r < 4; ++r) {
        int g = row0 + ty * 4 + r;
        #pragma unroll
        for (int c = 0; c < 4; ++c) {
            int cc = col0 + tx * 4 + c;
            float val = acc[r][c];
            if (MODE == 0) {
                int j = g >> 1, b = g & 1;
                __hip_bfloat16* k_bf = (__hip_bfloat16*)out0v;
                __hip_bfloat16* vt_bf = (__hip_bfloat16*)out1v;
                if (cc < H * DH) {
                    int h = cc >> 6, d = cc & 63;
                    k_bf[(((size_t)b * H + h) * J + j) * DH + d] = __float2bfloat16(val);
                } else {
                    int c2 = cc - H * DH;
                    int h = c2 >> 6, d = c2 & 63;
                    vt_bf[(((size_t)b * H + h) * DH + d) * J + j] = __float2bfloat16(val);
                }
            } else if (MODE == 1) {
                int i = g >> 1, b = g & 1;
                int h = cc >> 6, d = cc & 63;
                size_t o = (((size_t)b * H + h) * S + i) * DH + d;
                ((__hip_bfloat16*)out0v)[o] = __float2bfloat16((val + uvec[cc]) * SCALE);
                ((__hip_bfloat16*)out1v)[o] = __float2bfloat16((val + vvec[cc]) * SCALE);
            } else if (MODE == 2) {
                int h = cc >> 6, d = cc & 63;
                ((__hip_bfloat16*)out0v)[((size_t)h * J + g) * DH + d] = __float2bfloat16(val);
            } else {
                ((float*)out0v)[(size_t)g * D + cc] = val;
            }
        }
    }
}

// ---------------------------------------------------------------------------
// MFMA attention. Block = 16 query rows (i0..i0+15) for one (b,h). 256 thr.
// LDS: 16 x 2048 fp16 logits, XOR-swizzled: elem (m,c) at m*2048 + (c ^ (m<<3)).
// content: scores[m][j]  = Qu[i0+m].K[j]            (MFMA, direct write)
// pos main: Z[m][u] = Qv[i0+m].R[u]  -> scores[m][i0+m+u-1023]   if col>=0
// pos wrap: Z'[m][u]= Qv[i0+m+1].R[u]-> scores[m][i0+m+u+1026]   if col<J
//   (main/wrap cols partition [0,J) minus the zero column 1025+i exactly)
// softmax rows in-place (fp16 logits -> bf16 probs, normalized), PV via MFMA
// with vt_bf pre-transposed [b][h][d][j].
// ---------------------------------------------------------------------------
__device__ __forceinline__ int sidx(int m, int c) {
    return (m << 11) + (c ^ (m << 3));
}

__global__ __launch_bounds__(256)
void attn_mfma(const short* __restrict__ qu_bf, const short* __restrict__ qv_bf,
               const short* __restrict__ k_bf,  const short* __restrict__ vt_bf,
               const short* __restrict__ r_bf,  float* __restrict__ o_ws)
{
    __shared__ unsigned short sc[16 * 2048];   // 64 KB exactly
    __half* sch = (__half*)sc;

    const int i0  = blockIdx.x * 16;
    const int bh  = blockIdx.y;
    const int h   = bh & (H - 1);
    const int b   = bh >> 4;
    const int tid = threadIdx.x;
    const int w    = tid >> 6;
    const int lane = tid & 63;
    const int lm   = lane & 15;     // m (A) or n (B) or col (C/D)
    const int lq   = lane >> 4;     // quad

    // ---- A fragments (per-lane row loads; no alignment requirement) ----
    const short* qup = qu_bf + ((size_t)(bh * S + i0 + lm)) * DH + lq * 8;
    bf16x8 au0 = *(const bf16x8*)qup;
    bf16x8 au1 = *(const bf16x8*)(qup + 32);
    const short* qvp = qv_bf + ((size_t)(bh * S + i0 + lm)) * DH + lq * 8;
    bf16x8 av0 = *(const bf16x8*)qvp;
    bf16x8 av1 = *(const bf16x8*)(qvp + 32);
    int r1 = i0 + 1 + lm; if (r1 > S - 1) r1 = S - 1;   // clamped row is always masked out
    const short* qwp = qv_bf + ((size_t)(bh * S + r1)) * DH + lq * 8;
    bf16x8 aw0 = *(const bf16x8*)qwp;
    bf16x8 aw1 = *(const bf16x8*)(qwp + 32);

    // ---- content ----
    const short* kbase = k_bf + (size_t)bh * J * DH;
    for (int t = w; t < 128; t += 4) {
        int j0 = t * 16;
        const short* kp = kbase + (size_t)(j0 + lm) * DH + lq * 8;
        bf16x8 b0 = *(const bf16x8*)kp;
        bf16x8 b1 = *(const bf16x8*)(kp + 32);
        f32x4 c = {0.f, 0.f, 0.f, 0.f};
        c = __builtin_amdgcn_mfma_f32_16x16x32_bf16(au0, b0, c, 0, 0, 0);
        c = __builtin_amdgcn_mfma_f32_16x16x32_bf16(au1, b1, c, 0, 0, 0);
        int col = j0 + lm;
        #pragma unroll
        for (int r = 0; r < 4; ++r) {
            int m = lq * 4 + r;
            sch[sidx(m, col)] = __float2half(c[r]);
        }
    }
    __syncthreads();

    // ---- pos main ----
    const short* rbase = r_bf + (size_t)h * J * DH;
    int t0 = (1008 - i0) >> 4; if (t0 < 0) t0 = 0;
    for (int t = t0 + w; t < 128; t += 4) {
        int u0 = t * 16;
        const short* rp = rbase + (size_t)(u0 + lm) * DH + lq * 8;
        bf16x8 b0 = *(const bf16x8*)rp;
        bf16x8 b1 = *(const bf16x8*)(rp + 32);
        f32x4 c = {0.f, 0.f, 0.f, 0.f};
        c = __builtin_amdgcn_mfma_f32_16x16x32_bf16(av0, b0, c, 0, 0, 0);
        c = __builtin_amdgcn_mfma_f32_16x16x32_bf16(av1, b1, c, 0, 0, 0);
        int cbase = i0 + u0 + lm - 1023;
        #pragma unroll
        for (int r = 0; r < 4; ++r) {
            int m = lq * 4 + r;
            int col = cbase + m;
            if (col >= 0) {
                int idx = sidx(m, col);
                sch[idx] = __float2half(__half2float(sch[idx]) + c[r]);
            }
        }
    }

    // ---- pos wrap (cols disjoint from main; same barrier epoch is safe) ----
    int t1 = (1037 - i0) >> 4;
    for (int t = w; t < t1; t += 4) {
        int u0 = t * 16;
        const short* rp = rbase + (size_t)(u0 + lm) * DH + lq * 8;
        bf16x8 b0 = *(const bf16x8*)rp;
        bf16x8 b1 = *(const bf16x8*)(rp + 32);
        f32x4 c = {0.f, 0.f, 0.f, 0.f};
        c = __builtin_amdgcn_mfma_f32_16x16x32_bf16(aw0, b0, c, 0, 0, 0);
        c = __builtin_amdgcn_mfma_f32_16x16x32_bf16(aw1, b1, c, 0, 0, 0);
        int cbase = i0 + u0 + lm + 1026;
        #pragma unroll
        for (int r = 0; r < 4; ++r) {
            int m = lq * 4 + r;
            int col = cbase + m;
            if (col < J) {
                int idx = sidx(m, col);
                sch[idx] = __float2half(__half2float(sch[idx]) + c[r]);
            }
        }
    }
    __syncthreads();

    // ---- softmax: 16 threads per row; probs normalized in place as bf16 ----
    {
        const int row = tid >> 4;
        const int cw  = (tid & 15) * 8;
        float mx = -1e30f;
        for (int c = cw; c < 2048; c += 128) {
            h16x8 v = *(const h16x8*)(sc + sidx(row, c));
            #pragma unroll
            for (int k = 0; k < 8; ++k) mx = fmaxf(mx, (float)v[k]);
        }
        #pragma unroll
        for (int off = 1; off < 16; off <<= 1) mx = fmaxf(mx, __shfl_xor(mx, off));
        float ssum = 0.f;
        for (int c = cw; c < 2048; c += 128) {
            int idx = sidx(row, c);
            h16x8 v = *(const h16x8*)(sc + idx);
            h16x8 e;
            #pragma unroll
            for (int k = 0; k < 8; ++k) {
                float ex = __expf((float)v[k] - mx);
                ssum += ex;
                e[k] = (_Float16)ex;
            }
            *(h16x8*)(sc + idx) = e;
        }
        #pragma unroll
        for (int off = 1; off < 16; off <<= 1) ssum += __shfl_xor(ssum, off);
        float inv = 1.0f / ssum;
        for (int c = cw; c < 2048; c += 128) {
            int idx = sidx(row, c);
            h16x8 v = *(const h16x8*)(sc + idx);
            us8 o;
            #pragma unroll
            for (int k = 0; k < 8; ++k) o[k] = f2bf((float)v[k] * inv);
            *(us8*)(sc + idx) = o;
        }
    }
    __syncthreads();

    // ---- PV: each wave owns one 16-wide d slice; A = probs (LDS), B = Vt ----
    const short* vtb = vt_bf + ((size_t)bh * DH + w * 16 + lm) * J;
    f32x4 acc0 = {0.f, 0.f, 0.f, 0.f}, acc1 = {0.f, 0.f, 0.f, 0.f};
    for (int j0 = 0; j0 < J; j0 += 64) {
        bf16x8 a0 = *(const bf16x8*)(sc + sidx(lm, j0 + lq * 8));
        bf16x8 bv0 = *(const bf16x8*)(vtb + j0 + lq * 8);
        acc0 = __builtin_amdgcn_mfma_f32_16x16x32_bf16(a0, bv0, acc0, 0, 0, 0);
        bf16x8 a1 = *(const bf16x8*)(sc + sidx(lm, j0 + 32 + lq * 8));
        bf16x8 bv1 = *(const bf16x8*)(vtb + j0 + 32 + lq * 8);
        acc1 = __builtin_amdgcn_mfma_f32_16x16x32_bf16(a1, bv1, acc1, 0, 0, 0);
    }
    int dcol = w * 16 + lm;
    #pragma unroll
    for (int r = 0; r < 4; ++r) {
        int m = lq * 4 + r;
        o_ws[((size_t)(i0 + m) * B + b) * (H * DH) + h * DH + dcol] = acc0[r] + acc1[r];
    }
}

// ---------------------------------------------------------------------------
extern "C" void kernel_launch(void* const* d_in, const int* in_sizes, int n_in,
                              void* d_out, int out_size, void* d_ws, size_t ws_size,
                              hipStream_t stream)
{
    const float* x    = (const float*)d_in[0];   // [S, B, D]
    const float* pemb = (const float*)d_in[1];   // [S+M, D]
    const float* mem  = (const float*)d_in[2];   // [M, B, D]
    const float* u    = (const float*)d_in[3];   // [H, DH]
    const float* v    = (const float*)d_in[4];   // [H, DH]
    const float* Wkv  = (const float*)d_in[5];   // [D, 2*H*DH]
    const float* Wq   = (const float*)d_in[6];   // [D, H*DH]
    const float* Wpos = (const float*)d_in[7];   // [D, H*DH]
    const float* Wout = (const float*)d_in[8];   // [H*DH, D]
    float* out = (float*)d_out;                  // [S, B, D]

    char* p = (char*)d_ws;
    __hip_bfloat16* k_bf  = (__hip_bfloat16*)p; p += (size_t)B * H * J * DH * 2;  // 8 MB
    __hip_bfloat16* vt_bf = (__hip_bfloat16*)p; p += (size_t)B * H * J * DH * 2;  // 8 MB
    __hip_bfloat16* qu_bf = (__hip_bfloat16*)p; p += (size_t)B * H * S * DH * 2;  // 4 MB
    __hip_bfloat16* qv_bf = (__hip_bfloat16*)p; p += (size_t)B * H * S * DH * 2;  // 4 MB
    __hip_bfloat16* r_bf  = (__hip_bfloat16*)p; p += (size_t)H * J * DH * 2;      // 4 MB
    float*          o_ws  = (float*)p;                                            // 8 MB

    // kv projection
    gemm_k<0><<<dim3((2 * H * DH) / 64, (J * B) / 64), 256, 0, stream>>>(
        mem, x, Wkv, 2 * H * DH, k_bf, vt_bf, nullptr, nullptr, M * B);
    // q projection (+u, +v, *SCALE)
    gemm_k<1><<<dim3((H * DH) / 64, (S * B) / 64), 256, 0, stream>>>(
        x, nullptr, Wq, H * DH, qu_bf, qv_bf, u, v, 0);
    // r projection
    gemm_k<2><<<dim3((H * DH) / 64, J / 64), 256, 0, stream>>>(
        pemb, nullptr, Wpos, H * DH, r_bf, nullptr, nullptr, nullptr, 0);
    // MFMA rel-shift attention
    attn_mfma<<<dim3(S / 16, B * H), 256, 0, stream>>>(
        (const short*)qu_bf, (const short*)qv_bf, (const short*)k_bf,
        (const short*)vt_bf, (const short*)r_bf, o_ws);
    // output projection
    gemm_k<3><<<dim3(D / 64, (S * B) / 64), 256, 0, stream>>>(
        o_ws, nullptr, Wout, D, out, nullptr, nullptr, nullptr, 0);
}

// Round 3
// 404.816 us; speedup vs baseline: 20.1105x; 2.9332x over previous
//
#include <hip/hip_runtime.h>
#include <hip/hip_bf16.h>
#include <hip/hip_fp16.h>
#include <math.h>

#define D    1024
#define H    16
#define DH   64
#define S    1024
#define M    1024
#define B    2
#define J    2048          // M + S
#define SCALE 0.125f       // 1/sqrt(64)

typedef __attribute__((ext_vector_type(8))) short        bf16x8;
typedef __attribute__((ext_vector_type(4))) short        s16x4;
typedef __attribute__((ext_vector_type(8))) _Float16     h16x8;
typedef __attribute__((ext_vector_type(8))) unsigned short us8;
typedef __attribute__((ext_vector_type(4))) float        f32x4;

__device__ __forceinline__ unsigned short f2bf(float f) {
    __hip_bfloat16 t = __float2bfloat16(f);
    unsigned short r; __builtin_memcpy(&r, &t, 2); return r;
}
__device__ __forceinline__ short f2bs(float f) {
    __hip_bfloat16 t = __float2bfloat16(f);
    short r; __builtin_memcpy(&r, &t, 2); return r;
}

// async global->LDS, 16 bytes per lane
__device__ __forceinline__ void g2l16(const short* g, short* l) {
    __builtin_amdgcn_global_load_lds(
        (const __attribute__((address_space(1))) unsigned int*)g,
        (__attribute__((address_space(3))) unsigned int*)l, 16, 0, 0);
}

// ---------------------------------------------------------------------------
// fp32 -> bf16 flat convert: a_bf[0:2M) <- mem, a_bf[2M:4M) <- x, p_bf <- pemb
// ---------------------------------------------------------------------------
__global__ __launch_bounds__(256)
void conv_copy(const float* __restrict__ mem, const float* __restrict__ x,
               const float* __restrict__ pemb,
               short* __restrict__ a_bf, short* __restrict__ p_bf)
{
    const int idx = (blockIdx.x * 256 + threadIdx.x) * 4;   // 0 .. 6M
    const int TWO_M = 2 * 1024 * 1024;
    float4 v;
    short* dst;
    if (idx < TWO_M)          { v = *(const float4*)(mem  + idx);          dst = a_bf + idx; }
    else if (idx < 2 * TWO_M) { v = *(const float4*)(x    + idx - TWO_M);  dst = a_bf + idx; }
    else                      { v = *(const float4*)(pemb + idx - 2*TWO_M); dst = p_bf + idx - 2*TWO_M; }
    s16x4 o = { f2bs(v.x), f2bs(v.y), f2bs(v.z), f2bs(v.w) };
    *(s16x4*)dst = o;
}

// ---------------------------------------------------------------------------
// Weight transpose + convert: W[k][n] fp32 -> Wt[n][k] bf16 (64x64 LDS tiles)
// tiles: [0,512) Wkv(N=2048), [512,768) Wq, [768,1024) Wpos, [1024,1280) Wout
// ---------------------------------------------------------------------------
__global__ __launch_bounds__(256)
void wtrans(const float* __restrict__ Wkv, const float* __restrict__ Wq,
            const float* __restrict__ Wpos, const float* __restrict__ Wout,
            short* __restrict__ wkvt, short* __restrict__ wqt,
            short* __restrict__ wpt,  short* __restrict__ wot)
{
    __shared__ float t[64][65];
    const int tile = blockIdx.x;
    const int tid  = threadIdx.x;
    const float* src; short* dst; int N, t0;
    if (tile < 512)       { src = Wkv;  dst = wkvt; N = 2048; t0 = tile; }
    else if (tile < 768)  { src = Wq;   dst = wqt;  N = 1024; t0 = tile - 512; }
    else if (tile < 1024) { src = Wpos; dst = wpt;  N = 1024; t0 = tile - 768; }
    else                  { src = Wout; dst = wot;  N = 1024; t0 = tile - 1024; }
    const int ntn = N >> 6;
    const int k0 = (t0 / ntn) * 64, n0 = (t0 % ntn) * 64;
    #pragma unroll
    for (int e = tid; e < 4096; e += 256) {
        int r = e >> 6, c = e & 63;
        t[r][c] = src[(size_t)(k0 + r) * N + n0 + c];
    }
    __syncthreads();
    #pragma unroll
    for (int e = tid; e < 4096; e += 256) {
        int nr = e >> 6, kc = e & 63;
        dst[(size_t)(n0 + nr) * 1024 + k0 + kc] = f2bs(t[kc][nr]);
    }
}

// ---------------------------------------------------------------------------
// bf16 MFMA GEMM, m97 structure: BM=BN=128, BK=64, 256 thr (2x2 waves),
// global_load_lds(16B) staging with XOR chunk swizzle, 4x4 mfma_16x16x32 accs.
// C[m][n] = sum_k A[m][k] * Bt[n][k], K = 1024.
// MODE 0: kv proj   (M=4096, N=2048) -> k_bf [b][h][j][d], vt_bf [b][h][d][j]
// MODE 1: q proj    (M=2048, N=1024) -> qu/qv [b][h][i][d] = (q+u|v)*SCALE
// MODE 2: r proj    (M=2048, N=1024) -> r_bf [h][u][d]
// MODE 3: out proj  (M=2048, N=1024) -> fp32 out[m][n]
// ---------------------------------------------------------------------------
template<int MODE>
__global__ __launch_bounds__(256)
void gemm_mfma(const short* __restrict__ A, const short* __restrict__ Bt,
               void* __restrict__ out0v, void* __restrict__ out1v,
               const float* __restrict__ uvec, const float* __restrict__ vvec)
{
    __shared__ __align__(16) short As[128 * 64];
    __shared__ __align__(16) short Bs[128 * 64];

    const int bn0 = blockIdx.x * 128;
    const int bm0 = blockIdx.y * 128;
    const int tid = threadIdx.x;
    const int w    = tid >> 6;
    const int wy   = w >> 1, wx = w & 1;
    const int lane = tid & 63;
    const int lm   = lane & 15;
    const int lq   = lane >> 4;

    f32x4 acc[4][4];
    #pragma unroll
    for (int r = 0; r < 4; ++r)
        #pragma unroll
        for (int c = 0; c < 4; ++c)
            acc[r][c] = (f32x4){0.f, 0.f, 0.f, 0.f};

    for (int k0 = 0; k0 < 1024; k0 += 64) {
        const short* Ab = A  + (size_t)bm0 * 1024 + k0;
        const short* Bb = Bt + (size_t)bn0 * 1024 + k0;
        #pragma unroll
        for (int t = 0; t < 4; ++t) {
            int s = t * 256 + tid;
            int r = s >> 3, c = s & 7;
            int cg = c ^ (r & 7);
            g2l16(Ab + r * 1024 + cg * 8, As + s * 8);
            g2l16(Bb + r * 1024 + cg * 8, Bs + s * 8);
        }
        __syncthreads();   // drains vmcnt (global_load_lds) + barrier

        #pragma unroll
        for (int kk = 0; kk < 2; ++kk) {
            bf16x8 af[4], bg[4];
            #pragma unroll
            for (int r4 = 0; r4 < 4; ++r4) {
                int ar = wy * 64 + r4 * 16 + lm;
                int kc = kk * 4 + lq;
                af[r4] = *(const bf16x8*)(As + ((ar << 3) + (kc ^ (ar & 7))) * 8);
            }
            #pragma unroll
            for (int c4 = 0; c4 < 4; ++c4) {
                int br = wx * 64 + c4 * 16 + lm;
                int kc = kk * 4 + lq;
                bg[c4] = *(const bf16x8*)(Bs + ((br << 3) + (kc ^ (br & 7))) * 8);
            }
            #pragma unroll
            for (int r4 = 0; r4 < 4; ++r4)
                #pragma unroll
                for (int c4 = 0; c4 < 4; ++c4)
                    acc[r4][c4] = __builtin_amdgcn_mfma_f32_16x16x32_bf16(
                        af[r4], bg[c4], acc[r4][c4], 0, 0, 0);
        }
        __syncthreads();
    }

    // ---- epilogue ----
    #pragma unroll
    for (int r4 = 0; r4 < 4; ++r4) {
        #pragma unroll
        for (int c4 = 0; c4 < 4; ++c4) {
            const int n = bn0 + wx * 64 + c4 * 16 + lm;
            float ubias = 0.f, vbias = 0.f;
            if (MODE == 1) { ubias = uvec[n]; vbias = vvec[n]; }
            #pragma unroll
            for (int reg = 0; reg < 4; ++reg) {
                const int m = bm0 + wy * 64 + r4 * 16 + lq * 4 + reg;
                const float val = acc[r4][c4][reg];
                if (MODE == 0) {
                    int j = m >> 1, b = m & 1;
                    if (n < 1024) {
                        int h = n >> 6, d = n & 63;
                        ((short*)out0v)[(((size_t)b * H + h) * J + j) * DH + d] = f2bs(val);
                    } else {
                        int n2 = n - 1024, h = n2 >> 6, d = n2 & 63;
                        ((short*)out1v)[(((size_t)b * H + h) * DH + d) * J + j] = f2bs(val);
                    }
                } else if (MODE == 1) {
                    int i = m >> 1, b = m & 1;
                    int h = n >> 6, d = n & 63;
                    size_t o = (((size_t)b * H + h) * S + i) * DH + d;
                    ((short*)out0v)[o] = f2bs((val + ubias) * SCALE);
                    ((short*)out1v)[o] = f2bs((val + vbias) * SCALE);
                } else if (MODE == 2) {
                    int h = n >> 6, d = n & 63;
                    ((short*)out0v)[((size_t)h * J + m) * DH + d] = f2bs(val);
                } else {
                    ((float*)out0v)[(size_t)m * 1024 + n] = val;
                }
            }
        }
    }
}

// ---------------------------------------------------------------------------
// MFMA attention (unchanged from R1 except bf16 output). Block = 16 query
// rows for one (b,h); LDS 16x2048 fp16 logits, XOR-swizzled.
// ---------------------------------------------------------------------------
__device__ __forceinline__ int sidx(int m, int c) {
    return (m << 11) + (c ^ (m << 3));
}

__global__ __launch_bounds__(256)
void attn_mfma(const short* __restrict__ qu_bf, const short* __restrict__ qv_bf,
               const short* __restrict__ k_bf,  const short* __restrict__ vt_bf,
               const short* __restrict__ r_bf,  short* __restrict__ o_bf)
{
    __shared__ unsigned short sc[16 * 2048];   // 64 KB
    __half* sch = (__half*)sc;

    const int i0  = blockIdx.x * 16;
    const int bh  = blockIdx.y;
    const int h   = bh & (H - 1);
    const int b   = bh >> 4;
    const int tid = threadIdx.x;
    const int w    = tid >> 6;
    const int lane = tid & 63;
    const int lm   = lane & 15;
    const int lq   = lane >> 4;

    const short* qup = qu_bf + ((size_t)(bh * S + i0 + lm)) * DH + lq * 8;
    bf16x8 au0 = *(const bf16x8*)qup;
    bf16x8 au1 = *(const bf16x8*)(qup + 32);
    const short* qvp = qv_bf + ((size_t)(bh * S + i0 + lm)) * DH + lq * 8;
    bf16x8 av0 = *(const bf16x8*)qvp;
    bf16x8 av1 = *(const bf16x8*)(qvp + 32);
    int r1 = i0 + 1 + lm; if (r1 > S - 1) r1 = S - 1;   // clamped row is always masked
    const short* qwp = qv_bf + ((size_t)(bh * S + r1)) * DH + lq * 8;
    bf16x8 aw0 = *(const bf16x8*)qwp;
    bf16x8 aw1 = *(const bf16x8*)(qwp + 32);

    // ---- content ----
    const short* kbase = k_bf + (size_t)bh * J * DH;
    for (int t = w; t < 128; t += 4) {
        int j0 = t * 16;
        const short* kp = kbase + (size_t)(j0 + lm) * DH + lq * 8;
        bf16x8 b0 = *(const bf16x8*)kp;
        bf16x8 b1 = *(const bf16x8*)(kp + 32);
        f32x4 c = {0.f, 0.f, 0.f, 0.f};
        c = __builtin_amdgcn_mfma_f32_16x16x32_bf16(au0, b0, c, 0, 0, 0);
        c = __builtin_amdgcn_mfma_f32_16x16x32_bf16(au1, b1, c, 0, 0, 0);
        int col = j0 + lm;
        #pragma unroll
        for (int r = 0; r < 4; ++r) {
            int m = lq * 4 + r;
            sch[sidx(m, col)] = __float2half(c[r]);
        }
    }
    __syncthreads();

    // ---- pos main: scores[m][i0+m+u-1023] += Qv[i0+m].R[u], col >= 0 ----
    const short* rbase = r_bf + (size_t)h * J * DH;
    int t0 = (1008 - i0) >> 4; if (t0 < 0) t0 = 0;
    for (int t = t0 + w; t < 128; t += 4) {
        int u0 = t * 16;
        const short* rp = rbase + (size_t)(u0 + lm) * DH + lq * 8;
        bf16x8 b0 = *(const bf16x8*)rp;
        bf16x8 b1 = *(const bf16x8*)(rp + 32);
        f32x4 c = {0.f, 0.f, 0.f, 0.f};
        c = __builtin_amdgcn_mfma_f32_16x16x32_bf16(av0, b0, c, 0, 0, 0);
        c = __builtin_amdgcn_mfma_f32_16x16x32_bf16(av1, b1, c, 0, 0, 0);
        int cbase = i0 + u0 + lm - 1023;
        #pragma unroll
        for (int r = 0; r < 4; ++r) {
            int m = lq * 4 + r;
            int col = cbase + m;
            if (col >= 0) {
                int idx = sidx(m, col);
                sch[idx] = __float2half(__half2float(sch[idx]) + c[r]);
            }
        }
    }

    // ---- pos wrap: scores[m][i0+m+u+1026] += Qv[i0+m+1].R[u], col < J ----
    int t1 = (1037 - i0) >> 4;
    for (int t = w; t < t1; t += 4) {
        int u0 = t * 16;
        const short* rp = rbase + (size_t)(u0 + lm) * DH + lq * 8;
        bf16x8 b0 = *(const bf16x8*)rp;
        bf16x8 b1 = *(const bf16x8*)(rp + 32);
        f32x4 c = {0.f, 0.f, 0.f, 0.f};
        c = __builtin_amdgcn_mfma_f32_16x16x32_bf16(aw0, b0, c, 0, 0, 0);
        c = __builtin_amdgcn_mfma_f32_16x16x32_bf16(aw1, b1, c, 0, 0, 0);
        int cbase = i0 + u0 + lm + 1026;
        #pragma unroll
        for (int r = 0; r < 4; ++r) {
            int m = lq * 4 + r;
            int col = cbase + m;
            if (col < J) {
                int idx = sidx(m, col);
                sch[idx] = __float2half(__half2float(sch[idx]) + c[r]);
            }
        }
    }
    __syncthreads();

    // ---- softmax: 16 threads per row; fp16 logits -> normalized bf16 probs ----
    {
        const int row = tid >> 4;
        const int cw  = (tid & 15) * 8;
        float mx = -1e30f;
        for (int c = cw; c < 2048; c += 128) {
            h16x8 v = *(const h16x8*)(sc + sidx(row, c));
            #pragma unroll
            for (int k = 0; k < 8; ++k) mx = fmaxf(mx, (float)v[k]);
        }
        #pragma unroll
        for (int off = 1; off < 16; off <<= 1) mx = fmaxf(mx, __shfl_xor(mx, off));
        float ssum = 0.f;
        for (int c = cw; c < 2048; c += 128) {
            int idx = sidx(row, c);
            h16x8 v = *(const h16x8*)(sc + idx);
            h16x8 e;
            #pragma unroll
            for (int k = 0; k < 8; ++k) {
                float ex = __expf((float)v[k] - mx);
                ssum += ex;
                e[k] = (_Float16)ex;
            }
            *(h16x8*)(sc + idx) = e;
        }
        #pragma unroll
        for (int off = 1; off < 16; off <<= 1) ssum += __shfl_xor(ssum, off);
        float inv = 1.0f / ssum;
        for (int c = cw; c < 2048; c += 128) {
            int idx = sidx(row, c);
            h16x8 v = *(const h16x8*)(sc + idx);
            us8 o;
            #pragma unroll
            for (int k = 0; k < 8; ++k) o[k] = f2bf((float)v[k] * inv);
            *(us8*)(sc + idx) = o;
        }
    }
    __syncthreads();

    // ---- PV: wave owns 16-wide d slice; A = probs (LDS), B = Vt ----
    const short* vtb = vt_bf + ((size_t)bh * DH + w * 16 + lm) * J;
    f32x4 acc0 = {0.f, 0.f, 0.f, 0.f}, acc1 = {0.f, 0.f, 0.f, 0.f};
    for (int j0 = 0; j0 < J; j0 += 64) {
        bf16x8 a0 = *(const bf16x8*)(sc + sidx(lm, j0 + lq * 8));
        bf16x8 bv0 = *(const bf16x8*)(vtb + j0 + lq * 8);
        acc0 = __builtin_amdgcn_mfma_f32_16x16x32_bf16(a0, bv0, acc0, 0, 0, 0);
        bf16x8 a1 = *(const bf16x8*)(sc + sidx(lm, j0 + 32 + lq * 8));
        bf16x8 bv1 = *(const bf16x8*)(vtb + j0 + 32 + lq * 8);
        acc1 = __builtin_amdgcn_mfma_f32_16x16x32_bf16(a1, bv1, acc1, 0, 0, 0);
    }
    int dcol = w * 16 + lm;
    #pragma unroll
    for (int r = 0; r < 4; ++r) {
        int m = lq * 4 + r;
        o_bf[((size_t)(i0 + m) * B + b) * (H * DH) + h * DH + dcol] =
            f2bs(acc0[r] + acc1[r]);
    }
}

// ---------------------------------------------------------------------------
extern "C" void kernel_launch(void* const* d_in, const int* in_sizes, int n_in,
                              void* d_out, int out_size, void* d_ws, size_t ws_size,
                              hipStream_t stream)
{
    const float* x    = (const float*)d_in[0];   // [S, B, D]
    const float* pemb = (const float*)d_in[1];   // [S+M, D]
    const float* mem  = (const float*)d_in[2];   // [M, B, D]
    const float* u    = (const float*)d_in[3];   // [H, DH]
    const float* v    = (const float*)d_in[4];   // [H, DH]
    const float* Wkv  = (const float*)d_in[5];   // [D, 2*H*DH]
    const float* Wq   = (const float*)d_in[6];   // [D, H*DH]
    const float* Wpos = (const float*)d_in[7];   // [D, H*DH]
    const float* Wout = (const float*)d_in[8];   // [H*DH, D]
    float* out = (float*)d_out;                  // [S, B, D]

    char* p = (char*)d_ws;
    short* a_bf  = (short*)p; p += (size_t)4096 * 1024 * 2;   // 8 MB (mem||x)
    short* p_bf  = (short*)p; p += (size_t)2048 * 1024 * 2;   // 4 MB
    short* wkvt  = (short*)p; p += (size_t)2048 * 1024 * 2;   // 4 MB
    short* wqt   = (short*)p; p += (size_t)1024 * 1024 * 2;   // 2 MB
    short* wpt   = (short*)p; p += (size_t)1024 * 1024 * 2;   // 2 MB
    short* wot   = (short*)p; p += (size_t)1024 * 1024 * 2;   // 2 MB
    short* k_bf  = (short*)p; p += (size_t)B * H * J * DH * 2; // 8 MB
    short* vt_bf = (short*)p; p += (size_t)B * H * J * DH * 2; // 8 MB
    short* qu_bf = (short*)p; p += (size_t)B * H * S * DH * 2; // 4 MB
    short* qv_bf = (short*)p; p += (size_t)B * H * S * DH * 2; // 4 MB
    short* r_bf  = (short*)p; p += (size_t)H * J * DH * 2;     // 4 MB
    short* o_bf  = (short*)p;                                  // 4 MB

    conv_copy<<<6144, 256, 0, stream>>>(mem, x, pemb, a_bf, p_bf);
    wtrans<<<1280, 256, 0, stream>>>(Wkv, Wq, Wpos, Wout, wkvt, wqt, wpt, wot);

    // kv projection: M=4096, N=2048
    gemm_mfma<0><<<dim3(16, 32), 256, 0, stream>>>(a_bf, wkvt, k_bf, vt_bf, nullptr, nullptr);
    // q projection (+u,+v,*SCALE): M=2048, N=1024 (A = x half of a_bf)
    gemm_mfma<1><<<dim3(8, 16), 256, 0, stream>>>(a_bf + (size_t)2048 * 1024, wqt,
                                                  qu_bf, qv_bf, u, v);
    // r projection: M=2048, N=1024
    gemm_mfma<2><<<dim3(8, 16), 256, 0, stream>>>(p_bf, wpt, r_bf, nullptr, nullptr, nullptr);
    // attention
    attn_mfma<<<dim3(S / 16, B * H), 256, 0, stream>>>(qu_bf, qv_bf, k_bf, vt_bf, r_bf, o_bf);
    // output projection: M=2048, N=1024
    gemm_mfma<3><<<dim3(8, 16), 256, 0, stream>>>(o_bf, wot, out, nullptr, nullptr, nullptr);
}

// Round 4
// 372.781 us; speedup vs baseline: 21.8387x; 1.0859x over previous
//
#include <hip/hip_runtime.h>
#include <hip/hip_bf16.h>
#include <hip/hip_fp16.h>
#include <math.h>

#define D    1024
#define H    16
#define DH   64
#define S    1024
#define M    1024
#define B    2
#define J    2048          // M + S
#define SCALE 0.125f       // 1/sqrt(64)

typedef __attribute__((ext_vector_type(8))) short        bf16x8;
typedef __attribute__((ext_vector_type(4))) short        s16x4;
typedef __attribute__((ext_vector_type(8))) _Float16     h16x8;
typedef __attribute__((ext_vector_type(8))) unsigned short us8;
typedef __attribute__((ext_vector_type(4))) float        f32x4;

__device__ __forceinline__ unsigned short f2bf(float f) {
    __hip_bfloat16 t = __float2bfloat16(f);
    unsigned short r; __builtin_memcpy(&r, &t, 2); return r;
}
__device__ __forceinline__ short f2bs(float f) {
    __hip_bfloat16 t = __float2bfloat16(f);
    short r; __builtin_memcpy(&r, &t, 2); return r;
}

// async global->LDS, 16 bytes per lane
__device__ __forceinline__ void g2l16(const short* g, short* l) {
    __builtin_amdgcn_global_load_lds(
        (const __attribute__((address_space(1))) unsigned int*)g,
        (__attribute__((address_space(3))) unsigned int*)l, 16, 0, 0);
}

// ---------------------------------------------------------------------------
// prep: blocks [0,6144)  fp32->bf16 flat convert (mem||x -> a_bf, pemb -> p_bf)
//       blocks [6144,7424) 64x64 weight transpose+convert W[k][n] -> Wt[n][k]
// ---------------------------------------------------------------------------
__global__ __launch_bounds__(256)
void prep(const float* __restrict__ mem, const float* __restrict__ x,
          const float* __restrict__ pemb,
          const float* __restrict__ Wkv, const float* __restrict__ Wq,
          const float* __restrict__ Wpos, const float* __restrict__ Wout,
          short* __restrict__ a_bf, short* __restrict__ p_bf,
          short* __restrict__ wkvt, short* __restrict__ wqt,
          short* __restrict__ wpt,  short* __restrict__ wot)
{
    __shared__ float t[64][65];
    int blk = blockIdx.x;
    const int tid = threadIdx.x;
    if (blk < 6144) {
        const int idx = (blk * 256 + tid) * 4;
        const int TWO_M = 2 * 1024 * 1024;
        float4 v; short* dst;
        if (idx < TWO_M)          { v = *(const float4*)(mem  + idx);           dst = a_bf + idx; }
        else if (idx < 2 * TWO_M) { v = *(const float4*)(x    + idx - TWO_M);   dst = a_bf + idx; }
        else                      { v = *(const float4*)(pemb + idx - 2*TWO_M); dst = p_bf + idx - 2*TWO_M; }
        s16x4 o = { f2bs(v.x), f2bs(v.y), f2bs(v.z), f2bs(v.w) };
        *(s16x4*)dst = o;
        return;
    }
    blk -= 6144;
    const float* src; short* dst; int N, t0;
    if (blk < 512)       { src = Wkv;  dst = wkvt; N = 2048; t0 = blk; }
    else if (blk < 768)  { src = Wq;   dst = wqt;  N = 1024; t0 = blk - 512; }
    else if (blk < 1024) { src = Wpos; dst = wpt;  N = 1024; t0 = blk - 768; }
    else                 { src = Wout; dst = wot;  N = 1024; t0 = blk - 1024; }
    const int ntn = N >> 6;
    const int k0 = (t0 / ntn) * 64, n0 = (t0 % ntn) * 64;
    #pragma unroll
    for (int e = tid; e < 4096; e += 256) {
        int r = e >> 6, c = e & 63;
        t[r][c] = src[(size_t)(k0 + r) * N + n0 + c];
    }
    __syncthreads();
    #pragma unroll
    for (int e = tid; e < 4096; e += 256) {
        int nr = e >> 6, kc = e & 63;
        dst[(size_t)(n0 + nr) * 1024 + k0 + kc] = f2bs(t[kc][nr]);
    }
}

// ---------------------------------------------------------------------------
// Shared MFMA GEMM core: BM=BN=128, BK=64, 256 thr, K=1024.
// acc[r4][c4] over 16x16 tiles; XOR chunk-swizzled LDS staging via g2l16.
// ---------------------------------------------------------------------------
__device__ __forceinline__ void gemm_core(const short* __restrict__ A,
                                          const short* __restrict__ Bt,
                                          short* As, short* Bs,
                                          int bm0, int bn0, int tid,
                                          f32x4 acc[4][4])
{
    const int w    = tid >> 6;
    const int wy   = w >> 1, wx = w & 1;
    const int lane = tid & 63;
    const int lm   = lane & 15;
    const int lq   = lane >> 4;

    for (int k0 = 0; k0 < 1024; k0 += 64) {
        const short* Ab = A  + (size_t)bm0 * 1024 + k0;
        const short* Bb = Bt + (size_t)bn0 * 1024 + k0;
        #pragma unroll
        for (int t = 0; t < 4; ++t) {
            int s = t * 256 + tid;
            int r = s >> 3, c = s & 7;
            int cg = c ^ (r & 7);
            g2l16(Ab + r * 1024 + cg * 8, As + s * 8);
            g2l16(Bb + r * 1024 + cg * 8, Bs + s * 8);
        }
        __syncthreads();
        #pragma unroll
        for (int kk = 0; kk < 2; ++kk) {
            bf16x8 af[4], bg[4];
            #pragma unroll
            for (int r4 = 0; r4 < 4; ++r4) {
                int ar = wy * 64 + r4 * 16 + lm;
                int kc = kk * 4 + lq;
                af[r4] = *(const bf16x8*)(As + ((ar << 3) + (kc ^ (ar & 7))) * 8);
            }
            #pragma unroll
            for (int c4 = 0; c4 < 4; ++c4) {
                int br = wx * 64 + c4 * 16 + lm;
                int kc = kk * 4 + lq;
                bg[c4] = *(const bf16x8*)(Bs + ((br << 3) + (kc ^ (br & 7))) * 8);
            }
            #pragma unroll
            for (int r4 = 0; r4 < 4; ++r4)
                #pragma unroll
                for (int c4 = 0; c4 < 4; ++c4)
                    acc[r4][c4] = __builtin_amdgcn_mfma_f32_16x16x32_bf16(
                        af[r4], bg[c4], acc[r4][c4], 0, 0, 0);
        }
        __syncthreads();
    }
}

// ---------------------------------------------------------------------------
// Fused kv/q/r projections. blocks [0,512): kv (M=4096,N=2048);
// [512,640): q (M=2048,N=1024, +u/+v,*SCALE); [640,768): r (M=2048,N=1024).
// ---------------------------------------------------------------------------
__global__ __launch_bounds__(256)
void proj_fused(const short* __restrict__ a_bf, const short* __restrict__ p_bf,
                const short* __restrict__ wkvt, const short* __restrict__ wqt,
                const short* __restrict__ wpt,
                short* __restrict__ k_bf, short* __restrict__ vt_bf,
                short* __restrict__ qu_bf, short* __restrict__ qv_bf,
                short* __restrict__ r_bf,
                const float* __restrict__ uvec, const float* __restrict__ vvec)
{
    __shared__ __align__(16) short As[128 * 64];
    __shared__ __align__(16) short Bs[128 * 64];

    int blk = blockIdx.x;
    int mode, bx, by;
    const short *A, *Bt;
    if (blk < 512)      { mode = 0; bx = blk & 15; by = blk >> 4; A = a_bf; Bt = wkvt; }
    else if (blk < 640) { int b2 = blk - 512; mode = 1; bx = b2 & 7; by = b2 >> 3;
                          A = a_bf + (size_t)2048 * 1024; Bt = wqt; }
    else                { int b3 = blk - 640; mode = 2; bx = b3 & 7; by = b3 >> 3;
                          A = p_bf; Bt = wpt; }
    const int bn0 = bx * 128, bm0 = by * 128;
    const int tid = threadIdx.x;
    const int w = tid >> 6, wy = w >> 1, wx = w & 1;
    const int lane = tid & 63, lm = lane & 15, lq = lane >> 4;

    f32x4 acc[4][4];
    #pragma unroll
    for (int r = 0; r < 4; ++r)
        #pragma unroll
        for (int c = 0; c < 4; ++c) acc[r][c] = (f32x4){0.f, 0.f, 0.f, 0.f};

    gemm_core(A, Bt, As, Bs, bm0, bn0, tid, acc);

    #pragma unroll
    for (int r4 = 0; r4 < 4; ++r4) {
        #pragma unroll
        for (int c4 = 0; c4 < 4; ++c4) {
            const int n = bn0 + wx * 64 + c4 * 16 + lm;
            float ubias = 0.f, vbias = 0.f;
            if (mode == 1) { ubias = uvec[n]; vbias = vvec[n]; }
            #pragma unroll
            for (int reg = 0; reg < 4; ++reg) {
                const int m = bm0 + wy * 64 + r4 * 16 + lq * 4 + reg;
                const float val = acc[r4][c4][reg];
                if (mode == 0) {
                    int j = m >> 1, b = m & 1;
                    if (n < 1024) {
                        int h = n >> 6, d = n & 63;
                        k_bf[(((size_t)b * H + h) * J + j) * DH + d] = f2bs(val);
                    } else {
                        int n2 = n - 1024, h = n2 >> 6, d = n2 & 63;
                        vt_bf[(((size_t)b * H + h) * DH + d) * J + j] = f2bs(val);
                    }
                } else if (mode == 1) {
                    int i = m >> 1, b = m & 1;
                    int h = n >> 6, d = n & 63;
                    size_t o = (((size_t)b * H + h) * S + i) * DH + d;
                    qu_bf[o] = f2bs((val + ubias) * SCALE);
                    qv_bf[o] = f2bs((val + vbias) * SCALE);
                } else {
                    int h = n >> 6, d = n & 63;
                    r_bf[((size_t)h * J + m) * DH + d] = f2bs(val);
                }
            }
        }
    }
}

// ---------------------------------------------------------------------------
// Output projection: M=2048, N=1024, fp32 out.
// ---------------------------------------------------------------------------
__global__ __launch_bounds__(256)
void gemm_out(const short* __restrict__ A, const short* __restrict__ Bt,
              float* __restrict__ out)
{
    __shared__ __align__(16) short As[128 * 64];
    __shared__ __align__(16) short Bs[128 * 64];
    const int bn0 = blockIdx.x * 128, bm0 = blockIdx.y * 128;
    const int tid = threadIdx.x;
    const int w = tid >> 6, wy = w >> 1, wx = w & 1;
    const int lane = tid & 63, lm = lane & 15, lq = lane >> 4;

    f32x4 acc[4][4];
    #pragma unroll
    for (int r = 0; r < 4; ++r)
        #pragma unroll
        for (int c = 0; c < 4; ++c) acc[r][c] = (f32x4){0.f, 0.f, 0.f, 0.f};

    gemm_core(A, Bt, As, Bs, bm0, bn0, tid, acc);

    #pragma unroll
    for (int r4 = 0; r4 < 4; ++r4)
        #pragma unroll
        for (int c4 = 0; c4 < 4; ++c4) {
            const int n = bn0 + wx * 64 + c4 * 16 + lm;
            #pragma unroll
            for (int reg = 0; reg < 4; ++reg) {
                const int m = bm0 + wy * 64 + r4 * 16 + lq * 4 + reg;
                out[(size_t)m * 1024 + n] = acc[r4][c4][reg];
            }
        }
}

// ---------------------------------------------------------------------------
// MFMA attention, 512 threads (8 waves). Block = 16 query rows, one (b,h).
// LDS: 16x2048 fp16 logits, XOR-swizzled (c ^ (m<<3)). Unnormalized bf16
// probs; 1/sum folded into the PV partial-combine epilogue.
// ---------------------------------------------------------------------------
__device__ __forceinline__ int sidx(int m, int c) {
    return (m << 11) + (c ^ (m << 3));
}

__global__ __launch_bounds__(512)
void attn_mfma(const short* __restrict__ qu_bf, const short* __restrict__ qv_bf,
               const short* __restrict__ k_bf,  const short* __restrict__ vt_bf,
               const short* __restrict__ r_bf,  short* __restrict__ o_bf)
{
    __shared__ unsigned short sc[16 * 2048];   // 64 KB
    __half* sch = (__half*)sc;
    float*  scF = (float*)sc;                  // reused after PV reads

    const int i0  = blockIdx.x * 16;
    const int bh  = blockIdx.y;
    const int h   = bh & (H - 1);
    const int b   = bh >> 4;
    const int tid = threadIdx.x;
    const int w    = tid >> 6;       // 0..7
    const int lane = tid & 63;
    const int lm   = lane & 15;
    const int lq   = lane >> 4;

    const short* qup = qu_bf + ((size_t)(bh * S + i0 + lm)) * DH + lq * 8;
    bf16x8 au0 = *(const bf16x8*)qup;
    bf16x8 au1 = *(const bf16x8*)(qup + 32);
    const short* qvp = qv_bf + ((size_t)(bh * S + i0 + lm)) * DH + lq * 8;
    bf16x8 av0 = *(const bf16x8*)qvp;
    bf16x8 av1 = *(const bf16x8*)(qvp + 32);
    int r1 = i0 + 1 + lm; if (r1 > S - 1) r1 = S - 1;   // clamped row always masked
    const short* qwp = qv_bf + ((size_t)(bh * S + r1)) * DH + lq * 8;
    bf16x8 aw0 = *(const bf16x8*)qwp;
    bf16x8 aw1 = *(const bf16x8*)(qwp + 32);

    // ---- content ----
    const short* kbase = k_bf + (size_t)bh * J * DH;
    for (int t = w; t < 128; t += 8) {
        int j0 = t * 16;
        const short* kp = kbase + (size_t)(j0 + lm) * DH + lq * 8;
        bf16x8 b0 = *(const bf16x8*)kp;
        bf16x8 b1 = *(const bf16x8*)(kp + 32);
        f32x4 c = {0.f, 0.f, 0.f, 0.f};
        c = __builtin_amdgcn_mfma_f32_16x16x32_bf16(au0, b0, c, 0, 0, 0);
        c = __builtin_amdgcn_mfma_f32_16x16x32_bf16(au1, b1, c, 0, 0, 0);
        int col = j0 + lm;
        #pragma unroll
        for (int r = 0; r < 4; ++r) {
            int m = lq * 4 + r;
            sch[sidx(m, col)] = __float2half(c[r]);
        }
    }
    __syncthreads();

    // ---- pos main: scores[m][i0+m+u-1023] += Qv[i0+m].R[u], col >= 0 ----
    const short* rbase = r_bf + (size_t)h * J * DH;
    int t0 = (1008 - i0) >> 4; if (t0 < 0) t0 = 0;
    for (int t = t0 + w; t < 128; t += 8) {
        int u0 = t * 16;
        const short* rp = rbase + (size_t)(u0 + lm) * DH + lq * 8;
        bf16x8 b0 = *(const bf16x8*)rp;
        bf16x8 b1 = *(const bf16x8*)(rp + 32);
        f32x4 c = {0.f, 0.f, 0.f, 0.f};
        c = __builtin_amdgcn_mfma_f32_16x16x32_bf16(av0, b0, c, 0, 0, 0);
        c = __builtin_amdgcn_mfma_f32_16x16x32_bf16(av1, b1, c, 0, 0, 0);
        int cbase = i0 + u0 + lm - 1023;
        #pragma unroll
        for (int r = 0; r < 4; ++r) {
            int m = lq * 4 + r;
            int col = cbase + m;
            if (col >= 0) {
                int idx = sidx(m, col);
                sch[idx] = __float2half(__half2float(sch[idx]) + c[r]);
            }
        }
    }

    // ---- pos wrap: scores[m][i0+m+u+1026] += Qv[i0+m+1].R[u], col < J ----
    int t1 = (1037 - i0) >> 4;
    for (int t = w; t < t1; t += 8) {
        int u0 = t * 16;
        const short* rp = rbase + (size_t)(u0 + lm) * DH + lq * 8;
        bf16x8 b0 = *(const bf16x8*)rp;
        bf16x8 b1 = *(const bf16x8*)(rp + 32);
        f32x4 c = {0.f, 0.f, 0.f, 0.f};
        c = __builtin_amdgcn_mfma_f32_16x16x32_bf16(aw0, b0, c, 0, 0, 0);
        c = __builtin_amdgcn_mfma_f32_16x16x32_bf16(aw1, b1, c, 0, 0, 0);
        int cbase = i0 + u0 + lm + 1026;
        #pragma unroll
        for (int r = 0; r < 4; ++r) {
            int m = lq * 4 + r;
            int col = cbase + m;
            if (col < J) {
                int idx = sidx(m, col);
                sch[idx] = __float2half(__half2float(sch[idx]) + c[r]);
            }
        }
    }
    __syncthreads();

    // ---- softmax: 32 threads/row; store unnormalized bf16 exp; keep 1/sum ----
    float invr;
    {
        const int row = tid >> 5;
        const int cw  = (tid & 31) * 8;
        float mx = -1e30f;
        for (int c = cw; c < 2048; c += 256) {
            h16x8 v = *(const h16x8*)(sc + sidx(row, c));
            #pragma unroll
            for (int k = 0; k < 8; ++k) mx = fmaxf(mx, (float)v[k]);
        }
        #pragma unroll
        for (int off = 1; off < 32; off <<= 1) mx = fmaxf(mx, __shfl_xor(mx, off));
        float ssum = 0.f;
        for (int c = cw; c < 2048; c += 256) {
            int idx = sidx(row, c);
            h16x8 v = *(const h16x8*)(sc + idx);
            us8 e;
            #pragma unroll
            for (int k = 0; k < 8; ++k) {
                float ex = __expf((float)v[k] - mx);
                ssum += ex;
                e[k] = f2bf(ex);
            }
            *(us8*)(sc + idx) = e;
        }
        #pragma unroll
        for (int off = 1; off < 32; off <<= 1) ssum += __shfl_xor(ssum, off);
        invr = 1.0f / ssum;
    }
    __syncthreads();

    // ---- PV: wave w -> d-slice (w&3), j-half (w>>2); partials in LDS ----
    const int dslice = w & 3, jh = w >> 2;
    const short* vtb = vt_bf + ((size_t)bh * DH + dslice * 16 + lm) * J;
    f32x4 acc0 = {0.f, 0.f, 0.f, 0.f}, acc1 = {0.f, 0.f, 0.f, 0.f};
    const int jbeg = jh * 1024;
    for (int j0 = jbeg; j0 < jbeg + 1024; j0 += 64) {
        bf16x8 a0 = *(const bf16x8*)(sc + sidx(lm, j0 + lq * 8));
        bf16x8 bv0 = *(const bf16x8*)(vtb + j0 + lq * 8);
        acc0 = __builtin_amdgcn_mfma_f32_16x16x32_bf16(a0, bv0, acc0, 0, 0, 0);
        bf16x8 a1 = *(const bf16x8*)(sc + sidx(lm, j0 + 32 + lq * 8));
        bf16x8 bv1 = *(const bf16x8*)(vtb + j0 + 32 + lq * 8);
        acc1 = __builtin_amdgcn_mfma_f32_16x16x32_bf16(a1, bv1, acc1, 0, 0, 0);
    }
    __syncthreads();   // all probs read; sc reusable as float scratch

    #pragma unroll
    for (int r = 0; r < 4; ++r) {
        int m = lq * 4 + r;
        scF[jh * 1024 + m * 64 + dslice * 16 + lm] = acc0[r] + acc1[r];
    }
    if ((tid & 31) == 0) scF[2048 + (tid >> 5)] = invr;
    __syncthreads();

    #pragma unroll
    for (int e = tid; e < 1024; e += 512) {
        int m = e >> 6, dc = e & 63;
        float val = (scF[e] + scF[1024 + e]) * scF[2048 + m];
        o_bf[((size_t)(i0 + m) * B + b) * (H * DH) + h * DH + dc] = f2bs(val);
    }
}

// ---------------------------------------------------------------------------
extern "C" void kernel_launch(void* const* d_in, const int* in_sizes, int n_in,
                              void* d_out, int out_size, void* d_ws, size_t ws_size,
                              hipStream_t stream)
{
    const float* x    = (const float*)d_in[0];   // [S, B, D]
    const float* pemb = (const float*)d_in[1];   // [S+M, D]
    const float* mem  = (const float*)d_in[2];   // [M, B, D]
    const float* u    = (const float*)d_in[3];   // [H, DH]
    const float* v    = (const float*)d_in[4];   // [H, DH]
    const float* Wkv  = (const float*)d_in[5];   // [D, 2*H*DH]
    const float* Wq   = (const float*)d_in[6];   // [D, H*DH]
    const float* Wpos = (const float*)d_in[7];   // [D, H*DH]
    const float* Wout = (const float*)d_in[8];   // [H*DH, D]
    float* out = (float*)d_out;                  // [S, B, D]

    char* p = (char*)d_ws;
    short* a_bf  = (short*)p; p += (size_t)4096 * 1024 * 2;    // mem||x
    short* p_bf  = (short*)p; p += (size_t)2048 * 1024 * 2;
    short* wkvt  = (short*)p; p += (size_t)2048 * 1024 * 2;
    short* wqt   = (short*)p; p += (size_t)1024 * 1024 * 2;
    short* wpt   = (short*)p; p += (size_t)1024 * 1024 * 2;
    short* wot   = (short*)p; p += (size_t)1024 * 1024 * 2;
    short* k_bf  = (short*)p; p += (size_t)B * H * J * DH * 2;
    short* vt_bf = (short*)p; p += (size_t)B * H * J * DH * 2;
    short* qu_bf = (short*)p; p += (size_t)B * H * S * DH * 2;
    short* qv_bf = (short*)p; p += (size_t)B * H * S * DH * 2;
    short* r_bf  = (short*)p; p += (size_t)H * J * DH * 2;
    short* o_bf  = (short*)p;

    prep<<<7424, 256, 0, stream>>>(mem, x, pemb, Wkv, Wq, Wpos, Wout,
                                   a_bf, p_bf, wkvt, wqt, wpt, wot);
    proj_fused<<<768, 256, 0, stream>>>(a_bf, p_bf, wkvt, wqt, wpt,
                                        k_bf, vt_bf, qu_bf, qv_bf, r_bf, u, v);
    attn_mfma<<<dim3(S / 16, B * H), 512, 0, stream>>>(
        qu_bf, qv_bf, k_bf, vt_bf, r_bf, o_bf);
    gemm_out<<<dim3(8, 16), 256, 0, stream>>>(o_bf, wot, out);
}

// Round 5
// 363.761 us; speedup vs baseline: 22.3802x; 1.0248x over previous
//
#include <hip/hip_runtime.h>
#include <hip/hip_bf16.h>
#include <hip/hip_fp16.h>
#include <math.h>

#define D    1024
#define H    16
#define DH   64
#define S    1024
#define M    1024
#define B    2
#define J    2048          // M + S
#define SCALE 0.125f       // 1/sqrt(64)

typedef __attribute__((ext_vector_type(8))) short        bf16x8;
typedef __attribute__((ext_vector_type(4))) short        s16x4;
typedef __attribute__((ext_vector_type(8))) _Float16     h16x8;
typedef __attribute__((ext_vector_type(8))) unsigned short us8;
typedef __attribute__((ext_vector_type(4))) float        f32x4;

__device__ __forceinline__ unsigned short f2bf(float f) {
    __hip_bfloat16 t = __float2bfloat16(f);
    unsigned short r; __builtin_memcpy(&r, &t, 2); return r;
}
__device__ __forceinline__ short f2bs(float f) {
    __hip_bfloat16 t = __float2bfloat16(f);
    short r; __builtin_memcpy(&r, &t, 2); return r;
}

// async global->LDS, 16 bytes per lane
__device__ __forceinline__ void g2l16(const short* g, short* l) {
    __builtin_amdgcn_global_load_lds(
        (const __attribute__((address_space(1))) unsigned int*)g,
        (__attribute__((address_space(3))) unsigned int*)l, 16, 0, 0);
}

// ---------------------------------------------------------------------------
// prep: blocks [0,6144)  fp32->bf16 flat convert (mem||x -> a_bf, pemb -> p_bf)
//       blocks [6144,7424) 64x64 weight transpose+convert W[k][n] -> Wt[n][k]
// ---------------------------------------------------------------------------
__global__ __launch_bounds__(256)
void prep(const float* __restrict__ mem, const float* __restrict__ x,
          const float* __restrict__ pemb,
          const float* __restrict__ Wkv, const float* __restrict__ Wq,
          const float* __restrict__ Wpos, const float* __restrict__ Wout,
          short* __restrict__ a_bf, short* __restrict__ p_bf,
          short* __restrict__ wkvt, short* __restrict__ wqt,
          short* __restrict__ wpt,  short* __restrict__ wot)
{
    __shared__ float t[64][65];
    int blk = blockIdx.x;
    const int tid = threadIdx.x;
    if (blk < 6144) {
        const int idx = (blk * 256 + tid) * 4;
        const int TWO_M = 2 * 1024 * 1024;
        float4 v; short* dst;
        if (idx < TWO_M)          { v = *(const float4*)(mem  + idx);           dst = a_bf + idx; }
        else if (idx < 2 * TWO_M) { v = *(const float4*)(x    + idx - TWO_M);   dst = a_bf + idx; }
        else                      { v = *(const float4*)(pemb + idx - 2*TWO_M); dst = p_bf + idx - 2*TWO_M; }
        s16x4 o = { f2bs(v.x), f2bs(v.y), f2bs(v.z), f2bs(v.w) };
        *(s16x4*)dst = o;
        return;
    }
    blk -= 6144;
    const float* src; short* dst; int N, t0;
    if (blk < 512)       { src = Wkv;  dst = wkvt; N = 2048; t0 = blk; }
    else if (blk < 768)  { src = Wq;   dst = wqt;  N = 1024; t0 = blk - 512; }
    else if (blk < 1024) { src = Wpos; dst = wpt;  N = 1024; t0 = blk - 768; }
    else                 { src = Wout; dst = wot;  N = 1024; t0 = blk - 1024; }
    const int ntn = N >> 6;
    const int k0 = (t0 / ntn) * 64, n0 = (t0 % ntn) * 64;
    #pragma unroll
    for (int e = tid; e < 4096; e += 256) {
        int r = e >> 6, c = e & 63;
        t[r][c] = src[(size_t)(k0 + r) * N + n0 + c];
    }
    __syncthreads();
    #pragma unroll
    for (int e = tid; e < 4096; e += 256) {
        int nr = e >> 6, kc = e & 63;
        dst[(size_t)(n0 + nr) * 1024 + k0 + kc] = f2bs(t[kc][nr]);
    }
}

// ---------------------------------------------------------------------------
// Shared MFMA GEMM core: BM=BN=128, BK=64, 256 thr, K=1024.
// ---------------------------------------------------------------------------
__device__ __forceinline__ void gemm_core(const short* __restrict__ A,
                                          const short* __restrict__ Bt,
                                          short* As, short* Bs,
                                          int bm0, int bn0, int tid,
                                          f32x4 acc[4][4])
{
    const int w    = tid >> 6;
    const int wy   = w >> 1, wx = w & 1;
    const int lane = tid & 63;
    const int lm   = lane & 15;
    const int lq   = lane >> 4;

    for (int k0 = 0; k0 < 1024; k0 += 64) {
        const short* Ab = A  + (size_t)bm0 * 1024 + k0;
        const short* Bb = Bt + (size_t)bn0 * 1024 + k0;
        #pragma unroll
        for (int t = 0; t < 4; ++t) {
            int s = t * 256 + tid;
            int r = s >> 3, c = s & 7;
            int cg = c ^ (r & 7);
            g2l16(Ab + r * 1024 + cg * 8, As + s * 8);
            g2l16(Bb + r * 1024 + cg * 8, Bs + s * 8);
        }
        __syncthreads();
        #pragma unroll
        for (int kk = 0; kk < 2; ++kk) {
            bf16x8 af[4], bg[4];
            #pragma unroll
            for (int r4 = 0; r4 < 4; ++r4) {
                int ar = wy * 64 + r4 * 16 + lm;
                int kc = kk * 4 + lq;
                af[r4] = *(const bf16x8*)(As + ((ar << 3) + (kc ^ (ar & 7))) * 8);
            }
            #pragma unroll
            for (int c4 = 0; c4 < 4; ++c4) {
                int br = wx * 64 + c4 * 16 + lm;
                int kc = kk * 4 + lq;
                bg[c4] = *(const bf16x8*)(Bs + ((br << 3) + (kc ^ (br & 7))) * 8);
            }
            #pragma unroll
            for (int r4 = 0; r4 < 4; ++r4)
                #pragma unroll
                for (int c4 = 0; c4 < 4; ++c4)
                    acc[r4][c4] = __builtin_amdgcn_mfma_f32_16x16x32_bf16(
                        af[r4], bg[c4], acc[r4][c4], 0, 0, 0);
        }
        __syncthreads();
    }
}

// ---------------------------------------------------------------------------
// Fused kv/q/r projections. blocks [0,512): kv (M=4096,N=2048);
//   kv with bx>=8 (pure V) runs OPERAND-SWAPPED so lanes traverse tokens ->
//   vt stores become contiguous 16B runs instead of 2B/4KB-stride scatter.
// [512,640): q (M=2048,N=1024, +u/+v,*SCALE); [640,768): r (M=2048,N=1024).
// ---------------------------------------------------------------------------
__global__ __launch_bounds__(256)
void proj_fused(const short* __restrict__ a_bf, const short* __restrict__ p_bf,
                const short* __restrict__ wkvt, const short* __restrict__ wqt,
                const short* __restrict__ wpt,
                short* __restrict__ k_bf, short* __restrict__ vt_bf,
                short* __restrict__ qu_bf, short* __restrict__ qv_bf,
                short* __restrict__ r_bf,
                const float* __restrict__ uvec, const float* __restrict__ vvec)
{
    __shared__ __align__(16) short As[128 * 64];
    __shared__ __align__(16) short Bs[128 * 64];

    int blk = blockIdx.x;
    int mode, bx, by;
    const short *A, *Bt;
    if (blk < 512)      { bx = blk & 15; by = blk >> 4;
                          if (bx >= 8) { mode = 4; A = wkvt; Bt = a_bf; }   // swapped V
                          else         { mode = 0; A = a_bf; Bt = wkvt; } }
    else if (blk < 640) { int b2 = blk - 512; mode = 1; bx = b2 & 7; by = b2 >> 3;
                          A = a_bf + (size_t)2048 * 1024; Bt = wqt; }
    else                { int b3 = blk - 640; mode = 2; bx = b3 & 7; by = b3 >> 3;
                          A = p_bf; Bt = wpt; }
    const int bn0 = (mode == 4) ? by * 128 : bx * 128;   // swapped: cols = tokens
    const int bm0 = (mode == 4) ? bx * 128 : by * 128;   // swapped: rows = n (weights)
    const int tid = threadIdx.x;
    const int w = tid >> 6, wy = w >> 1, wx = w & 1;
    const int lane = tid & 63, lm = lane & 15, lq = lane >> 4;

    f32x4 acc[4][4];
    #pragma unroll
    for (int r = 0; r < 4; ++r)
        #pragma unroll
        for (int c = 0; c < 4; ++c) acc[r][c] = (f32x4){0.f, 0.f, 0.f, 0.f};

    gemm_core(A, Bt, As, Bs, bm0, bn0, tid, acc);

    #pragma unroll
    for (int r4 = 0; r4 < 4; ++r4) {
        #pragma unroll
        for (int c4 = 0; c4 < 4; ++c4) {
            const int n = bn0 + wx * 64 + c4 * 16 + lm;
            float ubias = 0.f, vbias = 0.f;
            if (mode == 1) { ubias = uvec[n]; vbias = vvec[n]; }
            #pragma unroll
            for (int reg = 0; reg < 4; ++reg) {
                const int m = bm0 + wy * 64 + r4 * 16 + lq * 4 + reg;
                const float val = acc[r4][c4][reg];
                if (mode == 0) {
                    int j = m >> 1, b = m & 1;
                    int h = n >> 6, d = n & 63;          // bx<8 -> n<1024 always
                    k_bf[(((size_t)b * H + h) * J + j) * DH + d] = f2bs(val);
                } else if (mode == 4) {
                    // swapped: m = weight row (n-dim, >=1024), n = token
                    int n2 = m - 1024, h = n2 >> 6, d = n2 & 63;
                    int j = n >> 1, b = n & 1;
                    vt_bf[(((size_t)b * H + h) * DH + d) * J + j] = f2bs(val);
                } else if (mode == 1) {
                    int i = m >> 1, b = m & 1;
                    int h = n >> 6, d = n & 63;
                    size_t o = (((size_t)b * H + h) * S + i) * DH + d;
                    qu_bf[o] = f2bs((val + ubias) * SCALE);
                    qv_bf[o] = f2bs((val + vbias) * SCALE);
                } else {
                    int h = n >> 6, d = n & 63;
                    r_bf[((size_t)h * J + m) * DH + d] = f2bs(val);
                }
            }
        }
    }
}

// ---------------------------------------------------------------------------
// Output projection: M=2048, N=1024, fp32 out.
// ---------------------------------------------------------------------------
__global__ __launch_bounds__(256)
void gemm_out(const short* __restrict__ A, const short* __restrict__ Bt,
              float* __restrict__ out)
{
    __shared__ __align__(16) short As[128 * 64];
    __shared__ __align__(16) short Bs[128 * 64];
    const int bn0 = blockIdx.x * 128, bm0 = blockIdx.y * 128;
    const int tid = threadIdx.x;
    const int w = tid >> 6, wy = w >> 1, wx = w & 1;
    const int lane = tid & 63, lm = lane & 15, lq = lane >> 4;

    f32x4 acc[4][4];
    #pragma unroll
    for (int r = 0; r < 4; ++r)
        #pragma unroll
        for (int c = 0; c < 4; ++c) acc[r][c] = (f32x4){0.f, 0.f, 0.f, 0.f};

    gemm_core(A, Bt, As, Bs, bm0, bn0, tid, acc);

    #pragma unroll
    for (int r4 = 0; r4 < 4; ++r4)
        #pragma unroll
        for (int c4 = 0; c4 < 4; ++c4) {
            const int n = bn0 + wx * 64 + c4 * 16 + lm;
            #pragma unroll
            for (int reg = 0; reg < 4; ++reg) {
                const int m = bm0 + wy * 64 + r4 * 16 + lq * 4 + reg;
                out[(size_t)m * 1024 + n] = acc[r4][c4][reg];
            }
        }
}

// ---------------------------------------------------------------------------
// MFMA attention, 512 threads (8 waves). Block = 16 query rows, one (b,h).
// LDS: 16x2048 fp16 logits, XOR-swizzled (c ^ (m<<3)).
// Phase order: pos DIRECT-STORE (main+wrap+hole partition all cols) ->
// content (acc init from pos, overwrite final logits) -> softmax
// (unnormalized bf16 probs, 1/sum folded into combine) -> PV (4 acc chains).
// All MFMA loops batch 4+ independent global loads per group for MLP.
// ---------------------------------------------------------------------------
__device__ __forceinline__ int sidx(int m, int c) {
    return (m << 11) + (c ^ (m << 3));
}

__global__ __launch_bounds__(512)
void attn_mfma(const short* __restrict__ qu_bf, const short* __restrict__ qv_bf,
               const short* __restrict__ k_bf,  const short* __restrict__ vt_bf,
               const short* __restrict__ r_bf,  short* __restrict__ o_bf)
{
    __shared__ unsigned short sc[16 * 2048];   // 64 KB
    __half* sch = (__half*)sc;
    float*  scF = (float*)sc;                  // reused after PV reads

    const int i0  = blockIdx.x * 16;
    const int bh  = blockIdx.y;
    const int h   = bh & (H - 1);
    const int b   = bh >> 4;
    const int tid = threadIdx.x;
    const int w    = tid >> 6;       // 0..7
    const int lane = tid & 63;
    const int lm   = lane & 15;
    const int lq   = lane >> 4;

    const short* qup = qu_bf + ((size_t)(bh * S + i0 + lm)) * DH + lq * 8;
    bf16x8 au0 = *(const bf16x8*)qup;
    bf16x8 au1 = *(const bf16x8*)(qup + 32);
    const short* qvp = qv_bf + ((size_t)(bh * S + i0 + lm)) * DH + lq * 8;
    bf16x8 av0 = *(const bf16x8*)qvp;
    bf16x8 av1 = *(const bf16x8*)(qvp + 32);
    int r1 = i0 + 1 + lm; if (r1 > S - 1) r1 = S - 1;   // clamped row always masked
    const short* qwp = qv_bf + ((size_t)(bh * S + r1)) * DH + lq * 8;
    bf16x8 aw0 = *(const bf16x8*)qwp;
    bf16x8 aw1 = *(const bf16x8*)(qwp + 32);

    // ---- zero the pos hole column: row m, col i0+m+1025 ----
    if (tid < 16) {
        int hole = i0 + tid + 1025;
        if (hole < J) sc[sidx(tid, hole)] = 0;
    }

    const short* rbase = r_bf + (size_t)h * J * DH;

    // ---- pos main (direct store): scores[m][i0+m+u-1023] = Qv[i0+m].R[u] ----
    int t0 = (1008 - i0) >> 4; if (t0 < 0) t0 = 0;
    int t = t0 + w;
    for (; t + 8 < 128; t += 16) {
        const short* rp0 = rbase + (size_t)(t * 16 + lm) * DH + lq * 8;
        const short* rp1 = rbase + (size_t)((t + 8) * 16 + lm) * DH + lq * 8;
        bf16x8 b0 = *(const bf16x8*)rp0;
        bf16x8 b1 = *(const bf16x8*)(rp0 + 32);
        bf16x8 b2 = *(const bf16x8*)rp1;
        bf16x8 b3 = *(const bf16x8*)(rp1 + 32);
        f32x4 c0 = {0.f,0.f,0.f,0.f}, c1 = {0.f,0.f,0.f,0.f};
        c0 = __builtin_amdgcn_mfma_f32_16x16x32_bf16(av0, b0, c0, 0, 0, 0);
        c1 = __builtin_amdgcn_mfma_f32_16x16x32_bf16(av0, b2, c1, 0, 0, 0);
        c0 = __builtin_amdgcn_mfma_f32_16x16x32_bf16(av1, b1, c0, 0, 0, 0);
        c1 = __builtin_amdgcn_mfma_f32_16x16x32_bf16(av1, b3, c1, 0, 0, 0);
        int cb0 = i0 + t * 16 + lm - 1023;
        int cb1 = cb0 + 128;
        #pragma unroll
        for (int r = 0; r < 4; ++r) {
            int m = lq * 4 + r;
            int col0 = cb0 + m, col1 = cb1 + m;
            if (col0 >= 0) sch[sidx(m, col0)] = __float2half(c0[r]);
            if (col1 >= 0) sch[sidx(m, col1)] = __float2half(c1[r]);
        }
    }
    if (t < 128) {
        const short* rp = rbase + (size_t)(t * 16 + lm) * DH + lq * 8;
        bf16x8 b0 = *(const bf16x8*)rp;
        bf16x8 b1 = *(const bf16x8*)(rp + 32);
        f32x4 c = {0.f,0.f,0.f,0.f};
        c = __builtin_amdgcn_mfma_f32_16x16x32_bf16(av0, b0, c, 0, 0, 0);
        c = __builtin_amdgcn_mfma_f32_16x16x32_bf16(av1, b1, c, 0, 0, 0);
        int cb = i0 + t * 16 + lm - 1023;
        #pragma unroll
        for (int r = 0; r < 4; ++r) {
            int m = lq * 4 + r, col = cb + m;
            if (col >= 0) sch[sidx(m, col)] = __float2half(c[r]);
        }
    }

    // ---- pos wrap: scores[m][i0+m+u+1026] = Qv[i0+m+1].R[u], col < J ----
    int t1 = (1037 - i0) >> 4;
    t = w;
    for (; t + 8 < t1; t += 16) {
        const short* rp0 = rbase + (size_t)(t * 16 + lm) * DH + lq * 8;
        const short* rp1 = rbase + (size_t)((t + 8) * 16 + lm) * DH + lq * 8;
        bf16x8 b0 = *(const bf16x8*)rp0;
        bf16x8 b1 = *(const bf16x8*)(rp0 + 32);
        bf16x8 b2 = *(const bf16x8*)rp1;
        bf16x8 b3 = *(const bf16x8*)(rp1 + 32);
        f32x4 c0 = {0.f,0.f,0.f,0.f}, c1 = {0.f,0.f,0.f,0.f};
        c0 = __builtin_amdgcn_mfma_f32_16x16x32_bf16(aw0, b0, c0, 0, 0, 0);
        c1 = __builtin_amdgcn_mfma_f32_16x16x32_bf16(aw0, b2, c1, 0, 0, 0);
        c0 = __builtin_amdgcn_mfma_f32_16x16x32_bf16(aw1, b1, c0, 0, 0, 0);
        c1 = __builtin_amdgcn_mfma_f32_16x16x32_bf16(aw1, b3, c1, 0, 0, 0);
        int cb0 = i0 + t * 16 + lm + 1026;
        int cb1 = cb0 + 128;
        #pragma unroll
        for (int r = 0; r < 4; ++r) {
            int m = lq * 4 + r;
            int col0 = cb0 + m, col1 = cb1 + m;
            if (col0 < J) sch[sidx(m, col0)] = __float2half(c0[r]);
            if (col1 < J) sch[sidx(m, col1)] = __float2half(c1[r]);
        }
    }
    if (t < t1) {
        const short* rp = rbase + (size_t)(t * 16 + lm) * DH + lq * 8;
        bf16x8 b0 = *(const bf16x8*)rp;
        bf16x8 b1 = *(const bf16x8*)(rp + 32);
        f32x4 c = {0.f,0.f,0.f,0.f};
        c = __builtin_amdgcn_mfma_f32_16x16x32_bf16(aw0, b0, c, 0, 0, 0);
        c = __builtin_amdgcn_mfma_f32_16x16x32_bf16(aw1, b1, c, 0, 0, 0);
        int cb = i0 + t * 16 + lm + 1026;
        #pragma unroll
        for (int r = 0; r < 4; ++r) {
            int m = lq * 4 + r, col = cb + m;
            if (col < J) sch[sidx(m, col)] = __float2half(c[r]);
        }
    }
    __syncthreads();

    // ---- content: acc init from pos, 4-tile groups (8 loads in flight) ----
    const short* kbase = k_bf + (size_t)bh * J * DH;
    #pragma unroll 1
    for (int g = 0; g < 4; ++g) {
        const int tb = w + 32 * g;          // tiles tb, tb+8, tb+16, tb+24
        bf16x8 kb[8];
        #pragma unroll
        for (int q = 0; q < 4; ++q) {
            const short* kp = kbase + (size_t)((tb + 8 * q) * 16 + lm) * DH + lq * 8;
            kb[2 * q]     = *(const bf16x8*)kp;
            kb[2 * q + 1] = *(const bf16x8*)(kp + 32);
        }
        #pragma unroll
        for (int q = 0; q < 4; ++q) {
            int col = (tb + 8 * q) * 16 + lm;
            f32x4 c;
            #pragma unroll
            for (int r = 0; r < 4; ++r)
                c[r] = __half2float(sch[sidx(lq * 4 + r, col)]);
            c = __builtin_amdgcn_mfma_f32_16x16x32_bf16(au0, kb[2 * q], c, 0, 0, 0);
            c = __builtin_amdgcn_mfma_f32_16x16x32_bf16(au1, kb[2 * q + 1], c, 0, 0, 0);
            #pragma unroll
            for (int r = 0; r < 4; ++r)
                sch[sidx(lq * 4 + r, col)] = __float2half(c[r]);
        }
    }
    __syncthreads();

    // ---- softmax: 32 threads/row; store unnormalized bf16 exp; keep 1/sum ----
    float invr;
    {
        const int row = tid >> 5;
        const int cw  = (tid & 31) * 8;
        float mx = -1e30f;
        for (int c = cw; c < 2048; c += 256) {
            h16x8 v = *(const h16x8*)(sc + sidx(row, c));
            #pragma unroll
            for (int k = 0; k < 8; ++k) mx = fmaxf(mx, (float)v[k]);
        }
        #pragma unroll
        for (int off = 1; off < 32; off <<= 1) mx = fmaxf(mx, __shfl_xor(mx, off));
        float ssum = 0.f;
        for (int c = cw; c < 2048; c += 256) {
            int idx = sidx(row, c);
            h16x8 v = *(const h16x8*)(sc + idx);
            us8 e;
            #pragma unroll
            for (int k = 0; k < 8; ++k) {
                float ex = __expf((float)v[k] - mx);
                ssum += ex;
                e[k] = f2bf(ex);
            }
            *(us8*)(sc + idx) = e;
        }
        #pragma unroll
        for (int off = 1; off < 32; off <<= 1) ssum += __shfl_xor(ssum, off);
        invr = 1.0f / ssum;
    }
    __syncthreads();

    // ---- PV: wave w -> d-slice (w&3), j-half (w>>2); 4 acc chains ----
    const int dslice = w & 3, jh = w >> 2;
    const short* vtb = vt_bf + ((size_t)bh * DH + dslice * 16 + lm) * J;
    const int jbeg = jh * 1024;
    f32x4 pa0 = {0.f,0.f,0.f,0.f}, pa1 = {0.f,0.f,0.f,0.f};
    f32x4 pa2 = {0.f,0.f,0.f,0.f}, pa3 = {0.f,0.f,0.f,0.f};
    #pragma unroll 1
    for (int jo = 0; jo < 8; ++jo) {    // 128 j per iteration
        int j0 = jbeg + jo * 128;
        bf16x8 bv0 = *(const bf16x8*)(vtb + j0 +  0 + lq * 8);
        bf16x8 bv1 = *(const bf16x8*)(vtb + j0 + 32 + lq * 8);
        bf16x8 bv2 = *(const bf16x8*)(vtb + j0 + 64 + lq * 8);
        bf16x8 bv3 = *(const bf16x8*)(vtb + j0 + 96 + lq * 8);
        bf16x8 a0 = *(const bf16x8*)(sc + sidx(lm, j0 +  0 + lq * 8));
        bf16x8 a1 = *(const bf16x8*)(sc + sidx(lm, j0 + 32 + lq * 8));
        bf16x8 a2 = *(const bf16x8*)(sc + sidx(lm, j0 + 64 + lq * 8));
        bf16x8 a3 = *(const bf16x8*)(sc + sidx(lm, j0 + 96 + lq * 8));
        pa0 = __builtin_amdgcn_mfma_f32_16x16x32_bf16(a0, bv0, pa0, 0, 0, 0);
        pa1 = __builtin_amdgcn_mfma_f32_16x16x32_bf16(a1, bv1, pa1, 0, 0, 0);
        pa2 = __builtin_amdgcn_mfma_f32_16x16x32_bf16(a2, bv2, pa2, 0, 0, 0);
        pa3 = __builtin_amdgcn_mfma_f32_16x16x32_bf16(a3, bv3, pa3, 0, 0, 0);
    }
    __syncthreads();   // all probs read; sc reusable as float scratch

    #pragma unroll
    for (int r = 0; r < 4; ++r) {
        int m = lq * 4 + r;
        scF[jh * 1024 + m * 64 + dslice * 16 + lm] =
            pa0[r] + pa1[r] + pa2[r] + pa3[r];
    }
    if ((tid & 31) == 0) scF[2048 + (tid >> 5)] = invr;
    __syncthreads();

    #pragma unroll
    for (int e = tid; e < 1024; e += 512) {
        int m = e >> 6, dc = e & 63;
        float val = (scF[e] + scF[1024 + e]) * scF[2048 + m];
        o_bf[((size_t)(i0 + m) * B + b) * (H * DH) + h * DH + dc] = f2bs(val);
    }
}

// ---------------------------------------------------------------------------
extern "C" void kernel_launch(void* const* d_in, const int* in_sizes, int n_in,
                              void* d_out, int out_size, void* d_ws, size_t ws_size,
                              hipStream_t stream)
{
    const float* x    = (const float*)d_in[0];   // [S, B, D]
    const float* pemb = (const float*)d_in[1];   // [S+M, D]
    const float* mem  = (const float*)d_in[2];   // [M, B, D]
    const float* u    = (const float*)d_in[3];   // [H, DH]
    const float* v    = (const float*)d_in[4];   // [H, DH]
    const float* Wkv  = (const float*)d_in[5];   // [D, 2*H*DH]
    const float* Wq   = (const float*)d_in[6];   // [D, H*DH]
    const float* Wpos = (const float*)d_in[7];   // [D, H*DH]
    const float* Wout = (const float*)d_in[8];   // [H*DH, D]
    float* out = (float*)d_out;                  // [S, B, D]

    char* p = (char*)d_ws;
    short* a_bf  = (short*)p; p += (size_t)4096 * 1024 * 2;    // mem||x
    short* p_bf  = (short*)p; p += (size_t)2048 * 1024 * 2;
    short* wkvt  = (short*)p; p += (size_t)2048 * 1024 * 2;
    short* wqt   = (short*)p; p += (size_t)1024 * 1024 * 2;
    short* wpt   = (short*)p; p += (size_t)1024 * 1024 * 2;
    short* wot   = (short*)p; p += (size_t)1024 * 1024 * 2;
    short* k_bf  = (short*)p; p += (size_t)B * H * J * DH * 2;
    short* vt_bf = (short*)p; p += (size_t)B * H * J * DH * 2;
    short* qu_bf = (short*)p; p += (size_t)B * H * S * DH * 2;
    short* qv_bf = (short*)p; p += (size_t)B * H * S * DH * 2;
    short* r_bf  = (short*)p; p += (size_t)H * J * DH * 2;
    short* o_bf  = (short*)p;

    prep<<<7424, 256, 0, stream>>>(mem, x, pemb, Wkv, Wq, Wpos, Wout,
                                   a_bf, p_bf, wkvt, wqt, wpt, wot);
    proj_fused<<<768, 256, 0, stream>>>(a_bf, p_bf, wkvt, wqt, wpt,
                                        k_bf, vt_bf, qu_bf, qv_bf, r_bf, u, v);
    attn_mfma<<<dim3(S / 16, B * H), 512, 0, stream>>>(
        qu_bf, qv_bf, k_bf, vt_bf, r_bf, o_bf);
    gemm_out<<<dim3(8, 16), 256, 0, stream>>>(o_bf, wot, out);
}